// Round 3
// baseline (1032.698 us; speedup 1.0000x reference)
//
#include <hip/hip_runtime.h>
#include <hip/hip_bf16.h>
#include <stdint.h>

// B=4, N=256, H=D=256.  M = N*N = 65536 edges per batch.
// G-refactor: out[n,h] = sum_d G[n,d]*wvo[h,d] + w[n]*bvo[h] (+bo+res, LN)
//   G[n,d] = sum_m P[m,n]*S[m,d],  w[n] = sum_m P[m,n],  P = normalized relu scores.
// Eliminates the per-edge VO GEMM entirely (34 GF + its L2 walk).
#define NB 4
#define NN 256
#define DD 256
#define MM 65536

typedef __attribute__((ext_vector_type(8))) __bf16 bf16x8;
typedef __attribute__((ext_vector_type(4))) __bf16 bf16x4;
typedef __attribute__((ext_vector_type(4))) float f32x4;

__device__ __forceinline__ f32x4 mfma_bf16(bf16x8 a, bf16x8 b, f32x4 c) {
    return __builtin_amdgcn_mfma_f32_16x16x32_bf16(a, b, c, 0, 0, 0);
}

// fragment-linear index for a [256 rows][256 cols] B-matrix:
// frag (nt,kk), lane (q,ln) holds row nt*16+ln, cols kk*32+q*8..+8
__device__ __forceinline__ size_t fragidx(int row, int col) {
    int nt = row >> 4, ln = row & 15;
    int kk = col >> 5, q = (col >> 3) & 3, e = col & 7;
    return ((size_t)((nt * 8 + kk) * 64 + q * 16 + ln)) * 8 + e;
}

// ---------------- tiny precompute kernels ----------------

// zeroes accg (G, 1MB) + wg (4KB) which are contiguous: 263168 floats = 65792 float4
__global__ void zero_kernel(float* __restrict__ p) {
    reinterpret_cast<float4*>(p)[blockIdx.x * 256 + threadIdx.x] =
        make_float4(0.f, 0.f, 0.f, 0.f);
}

// fused: k = hs@Wk + bk ; kqf[row,e] = (Wq[e,:].k)/16 (frag-linear) ; cb[row] = (bq.k)/16
__global__ void kkq_kernel(const float* __restrict__ hs, const float* __restrict__ Wk,
                           const float* __restrict__ bk, const float* __restrict__ Wq,
                           const float* __restrict__ bq, __bf16* __restrict__ kqf,
                           float* __restrict__ cb) {
    const int row = blockIdx.x, t = threadIdx.x;   // row in [0, NB*NN)
    __shared__ float hr[256];
    __shared__ float kr[256];
    __shared__ float red[256];
    hr[t] = hs[(size_t)row * 256 + t];
    __syncthreads();
    float v = bk[t];
    for (int e = 0; e < 256; ++e)
        v = fmaf(hr[e], Wk[(size_t)e * 256 + t], v);
    kr[t] = v;
    red[t] = v * bq[t];
    __syncthreads();
    float u = 0.f;
    for (int d = 0; d < 256; ++d)
        u = fmaf(Wq[(size_t)t * 256 + d], kr[d], u);
    const int b = row >> 8, n = row & 255;
    kqf[(size_t)b * NN * DD + fragidx(n, t)] = (__bf16)(u * 0.0625f);
    for (int s = 128; s > 0; s >>= 1) {
        if (t < s) red[t] += red[t + s];
        __syncthreads();
    }
    if (t == 0) cb[row] = red[0] * 0.0625f;
}

// wvo[h,e] = sum_d Wv[e,d]*Wo[d,h] (plain [h][e] fp32) ; bvo[h] = bv.Wo[:,h]
__global__ void wvoprep_kernel(const float* __restrict__ Wv, const float* __restrict__ Wo,
                               const float* __restrict__ bv, float* __restrict__ wvo,
                               float* __restrict__ bvo) {
    const int h = blockIdx.x, t = threadIdx.x;
    __shared__ float woc[256];
    __shared__ float red[256];
    float wo = Wo[(size_t)t * 256 + h];
    woc[t] = wo;
    red[t] = bv[t] * wo;
    __syncthreads();
    float v = 0.f;
    for (int d = 0; d < 256; ++d)
        v = fmaf(Wv[(size_t)t * 256 + d], woc[d], v);
    wvo[(size_t)h * 256 + t] = v;
    for (int s = 128; s > 0; s >>= 1) {
        if (t < s) red[t] += red[t + s];
        __syncthreads();
    }
    if (t == 0) bvo[h] = red[0];
}

// ---------------- phase A (v4: scores only; P normalized + S repack) ----------------
// PT (blocked [m/8][n][8]) = normalized relu(scores)^T, bf16.
// ST (blocked [m/8][d][8]) = bf16(S) — the B-operand for the G contraction.
// wg[b,n] += sum_m P[m,n].
// One WG = 4 waves = 64 edge-rows; wave w owns rows [w*16, w*16+16).
__global__ __launch_bounds__(256, 3)
void phaseA_kernel(const float* __restrict__ S, const __bf16* __restrict__ kqf,
                   const float* __restrict__ cb, const float* __restrict__ mask,
                   __bf16* __restrict__ PT, __bf16* __restrict__ ST,
                   float* __restrict__ wg, int c0, int CHS) {
    const int t = threadIdx.x;
    const int b = blockIdx.y;
    const int w = t >> 6;
    const int lane = t & 63;
    const int q = lane >> 4;
    const int ln = lane & 15;
    const int mloc = blockIdx.x * 64 + w * 16;    // wave's base within chunk
    const int m0 = c0 + mloc;                     // global edge base for wave
    const int mb0 = mloc >> 3;                    // local m-block base

    // A-fragments: 16 rows straight from global fp32, convert to bf16
    bf16x8 af[8];
    const float* Ar = S + ((size_t)b * MM + m0 + ln) * DD + q * 8;
#pragma unroll
    for (int kk = 0; kk < 8; ++kk) {
        float4 u0 = *reinterpret_cast<const float4*>(Ar + kk * 32);
        float4 u1 = *reinterpret_cast<const float4*>(Ar + kk * 32 + 4);
        af[kk] = (bf16x8){(__bf16)u0.x, (__bf16)u0.y, (__bf16)u0.z, (__bf16)u0.w,
                          (__bf16)u1.x, (__bf16)u1.y, (__bf16)u1.z, (__bf16)u1.w};
    }

    // ST repack immediately (rows are L2-hot from the A-load):
    // chunk it: rows m0+aa*8..+8, cols d=(it&3)*64+lane -> coalesced 256B wave reads,
    // contiguous 1KB wave stores into blocked [m/8][d][8] bf16.
    __bf16* Sb = ST + (size_t)b * NN * CHS;
#pragma unroll
    for (int it = 0; it < 8; ++it) {
        const int aa = it >> 2;
        const int d = (it & 3) * 64 + lane;
        const float* Sr = S + ((size_t)b * MM + m0 + aa * 8) * DD + d;
        bf16x8 sv = {(__bf16)Sr[0],      (__bf16)Sr[DD],     (__bf16)Sr[2 * DD],
                     (__bf16)Sr[3 * DD], (__bf16)Sr[4 * DD], (__bf16)Sr[5 * DD],
                     (__bf16)Sr[6 * DD], (__bf16)Sr[7 * DD]};
        *reinterpret_cast<bf16x8*>(Sb + ((size_t)(mb0 + aa) * 256 + d) * 8) = sv;
    }

    // pairwise additive mask for this lane's 4 m-rows
    float m2[4];
#pragma unroll
    for (int r = 0; r < 4; ++r) {
        int mg = m0 + q * 4 + r;
        m2[r] = mask[b * NN + (mg >> 8)] * mask[b * NN + (mg & 255)];
    }

    const __bf16* kqb = kqf + (size_t)b * NN * DD + (size_t)lane * 8;
    const float* cbb = cb + b * NN + ln;

    // ---- scores GEMM: p[nt] = relu(S.kq^T/16 + cb + m2), rowsums in rs*
    f32x4 p[16];
    float rs0 = 0.f, rs1 = 0.f, rs2 = 0.f, rs3 = 0.f;
#pragma unroll
    for (int nt = 0; nt < 16; ++nt) {
        f32x4 a = {0.f, 0.f, 0.f, 0.f};
        const __bf16* kr = kqb + (size_t)nt * 4096;
#pragma unroll
        for (int kk = 0; kk < 8; ++kk) {
            bf16x8 bf = *reinterpret_cast<const bf16x8*>(kr + kk * 512);
            a = mfma_bf16(af[kk], bf, a);
        }
        const float cbv = cbb[nt * 16];
        a.x = fmaxf(a.x + cbv + m2[0], 0.f);
        a.y = fmaxf(a.y + cbv + m2[1], 0.f);
        a.z = fmaxf(a.z + cbv + m2[2], 0.f);
        a.w = fmaxf(a.w + cbv + m2[3], 0.f);
        rs0 += a.x; rs1 += a.y; rs2 += a.z; rs3 += a.w;
        p[nt] = a;
    }
    // rowsum over the 16 n-lanes; ref: probs / sum(probs+1e-12) == probs/(rowsum+256e-12)
#pragma unroll
    for (int off = 1; off < 16; off <<= 1) {
        rs0 += __shfl_xor(rs0, off);
        rs1 += __shfl_xor(rs1, off);
        rs2 += __shfl_xor(rs2, off);
        rs3 += __shfl_xor(rs3, off);
    }
    const float i0 = 1.f / (rs0 + 2.56e-10f);
    const float i1 = 1.f / (rs1 + 2.56e-10f);
    const float i2 = 1.f / (rs2 + 2.56e-10f);
    const float i3 = 1.f / (rs3 + 2.56e-10f);

    // ---- normalized P store + w accumulation
    __bf16* Pb = PT + (size_t)b * NN * CHS;
    const size_t so = (size_t)ln * 8 + (size_t)(q & 1) * 4;
#pragma unroll
    for (int nt = 0; nt < 16; ++nt) {
        float x0 = p[nt].x * i0, x1 = p[nt].y * i1, x2 = p[nt].z * i2, x3 = p[nt].w * i3;
        bf16x4 pv = {(__bf16)x0, (__bf16)x1, (__bf16)x2, (__bf16)x3};
        *reinterpret_cast<bf16x4*>(Pb + (size_t)(mb0 + (q >> 1)) * 2048
                                   + (size_t)nt * 128 + so) = pv;
        float wn = x0 + x1 + x2 + x3;          // col-partial over this lane's 4 rows
        wn += __shfl_xor(wn, 16);              // reduce over the 4 q-groups
        wn += __shfl_xor(wn, 32);
        if (q == 0) atomicAdd(&wg[b * NN + nt * 16 + ln], wn);
    }
}

// ---------------- phase B: G[n,d] += P^T @ S  (K = edge dim) ----------------
// Identical structure to before (B-operand is now ST). Blocked layout keeps every
// fragment load a coalesced 256-B segment; no LDS.
__global__ __launch_bounds__(256, 2)
void phaseB_kernel(const __bf16* __restrict__ PT, const __bf16* __restrict__ ST,
                   float* __restrict__ accg, int CHS) {
    const int t = threadIdx.x;
    const int b = blockIdx.z;
    const int w = t >> 6;
    const int lane = t & 63;
    const int q = lane >> 4;
    const int ln = lane & 15;
    const int n0 = (blockIdx.x >> 1) * 128 + (w >> 1) * 64;
    const int h0 = (blockIdx.x & 1) * 128 + (w & 1) * 64;
    const int g0 = blockIdx.y * 256;           // k-chunk of 2048 -> 256 blocks of 8

    f32x4 acc[16];
#pragma unroll
    for (int i = 0; i < 16; ++i) acc[i] = (f32x4){0.f, 0.f, 0.f, 0.f};

    const __bf16* Pb = PT + (size_t)b * NN * CHS;
    const __bf16* Vb = ST + (size_t)b * NN * CHS;
#pragma unroll 2
    for (int ks = 0; ks < 64; ++ks) {
        const __bf16* Pk = Pb + ((size_t)(g0 + ks * 4 + q) * 256 + n0 + ln) * 8;
        const __bf16* Vk = Vb + ((size_t)(g0 + ks * 4 + q) * 256 + h0 + ln) * 8;
        bf16x8 a[4], bb[4];
#pragma unroll
        for (int i = 0; i < 4; ++i)
            a[i] = *reinterpret_cast<const bf16x8*>(Pk + i * 128);
#pragma unroll
        for (int j = 0; j < 4; ++j)
            bb[j] = *reinterpret_cast<const bf16x8*>(Vk + j * 128);
#pragma unroll
        for (int i = 0; i < 4; ++i)
#pragma unroll
            for (int j = 0; j < 4; ++j)
                acc[i * 4 + j] = mfma_bf16(a[i], bb[j], acc[i * 4 + j]);
    }
    float* og = accg + (size_t)b * NN * DD;
#pragma unroll
    for (int i = 0; i < 4; ++i)
#pragma unroll
        for (int j = 0; j < 4; ++j) {
            f32x4 a = acc[i * 4 + j];
            int n = n0 + i * 16 + q * 4;
            int h = h0 + j * 16 + ln;
            atomicAdd(&og[(size_t)(n + 0) * DD + h], a.x);
            atomicAdd(&og[(size_t)(n + 1) * DD + h], a.y);
            atomicAdd(&og[(size_t)(n + 2) * DD + h], a.z);
            atomicAdd(&og[(size_t)(n + 3) * DD + h], a.w);
        }
}

// ---------------- epilogue: ctx = G@wvo^T + w*bvo, +bo, +residual, LayerNorm ----------
__global__ void epilogue_kernel(const float* __restrict__ Gg, const float* __restrict__ wg,
                                const float* __restrict__ wvo, const float* __restrict__ bvo,
                                const float* __restrict__ hs, const float* __restrict__ bo,
                                const float* __restrict__ g, const float* __restrict__ be,
                                float* __restrict__ out) {
    const int row = blockIdx.x, t = threadIdx.x;   // row = b*256 + n, t = h
    __shared__ float Grow[256];
    __shared__ float red[256];
    const size_t base = (size_t)row * 256;
    Grow[t] = Gg[base + t];
    __syncthreads();
    float acc = 0.f;
    const float* wr = wvo + (size_t)t * 256;
    for (int d = 0; d < 256; ++d)
        acc = fmaf(Grow[d], wr[d], acc);
    float x = acc + wg[row] * bvo[t] + bo[t] + hs[base + t];
    red[t] = x;
    __syncthreads();
    for (int s = 128; s > 0; s >>= 1) {
        if (t < s) red[t] += red[t + s];
        __syncthreads();
    }
    float mean = red[0] * (1.f / 256.f);
    __syncthreads();
    float d2 = x - mean;
    red[t] = d2 * d2;
    __syncthreads();
    for (int s = 128; s > 0; s >>= 1) {
        if (t < s) red[t] += red[t + s];
        __syncthreads();
    }
    float var = red[0] * (1.f / 256.f);
    out[base + t] = g[t] * d2 * rsqrtf(var + 1e-5f) + be[t];
}

// ---------------- host launch ----------------
extern "C" void kernel_launch(void* const* d_in, const int* in_sizes, int n_in,
                              void* d_out, int out_size, void* d_ws, size_t ws_size,
                              hipStream_t stream) {
    const float* hs   = (const float*)d_in[0];
    const float* S    = (const float*)d_in[1];
    const float* mask = (const float*)d_in[2];
    const float* Wq   = (const float*)d_in[3];
    const float* bq   = (const float*)d_in[4];
    const float* Wk   = (const float*)d_in[5];
    const float* bk   = (const float*)d_in[6];
    const float* Wv   = (const float*)d_in[7];
    const float* bv   = (const float*)d_in[8];
    const float* Wo   = (const float*)d_in[9];
    const float* bo   = (const float*)d_in[10];
    const float* g    = (const float*)d_in[11];
    const float* be   = (const float*)d_in[12];
    float* out = (float*)d_out;

    char* ws = (char*)d_ws;
    size_t off = 0;
    auto alloc = [&](size_t bytes) {
        void* p = ws + off;
        off += (bytes + 255) & ~(size_t)255;
        return p;
    };
    float*  accg = (float*)alloc((size_t)NB * NN * DD * 4);   // G accumulator (1 MB)
    float*  wg   = (float*)alloc((size_t)NB * NN * 4);        // w accumulator (contiguous)
    __bf16* kqf  = (__bf16*)alloc((size_t)NB * NN * DD * 2);
    float*  cb   = (float*)alloc((size_t)NB * NN * 4);
    float*  wvo  = (float*)alloc((size_t)NN * DD * 4);
    float*  bvo  = (float*)alloc((size_t)NN * 4);
    // chunk of the edge dim: cap at 32768 so a chunk's PT+ST (128 MiB) can stay
    // L3-resident between phaseA write and phaseB read; shrink if ws small.
    size_t rem = ws_size > off ? ws_size - off : 0;
    int CH = 32768;
    while (CH > 4096 && (size_t)CH * 4096 + 1024 > rem) CH >>= 1;
    __bf16* PT = (__bf16*)alloc((size_t)NB * CH * NN * 2);
    __bf16* ST = (__bf16*)alloc((size_t)NB * CH * NN * 2);

    zero_kernel<<<257, 256, 0, stream>>>(accg);   // zeroes accg + wg (contiguous)
    kkq_kernel<<<NB * NN, 256, 0, stream>>>(hs, Wk, bk, Wq, bq, kqf, cb);
    wvoprep_kernel<<<NN, 256, 0, stream>>>(Wv, Wo, bv, wvo, bvo);
    for (int c0 = 0; c0 < MM; c0 += CH) {
        phaseA_kernel<<<dim3(CH / 64, NB), 256, 0, stream>>>(S, kqf, cb, mask,
                                                             PT, ST, wg, c0, CH);
        phaseB_kernel<<<dim3(4, CH / 2048, NB), 256, 0, stream>>>(PT, ST, accg, CH);
    }
    epilogue_kernel<<<NB * NN, 256, 0, stream>>>(accg, wg, wvo, bvo, hs, bo, g, be, out);
}

// Round 5
// 843.850 us; speedup vs baseline: 1.2238x; 1.2238x over previous
//
#include <hip/hip_runtime.h>
#include <hip/hip_bf16.h>
#include <stdint.h>

// B=4, N=256, H=D=256.  M = N*N = 65536 edges per batch.
// G-refactor: out[n,h] = sum_d G[n,d]*wvo[h,d] + w[n]*bvo[h] (+bo+res, LN)
//   G[n,d] = sum_m P[m,n]*S[m,d],  w[n] = sum_m P[m,n],  P = normalized relu scores.
// v5: phaseA = v4 minus the wg atomic storm (2M same-address atomics -> stall);
//     w is now computed in phaseB from the P fragments (32K low-contention atomics).
//     phaseB k-split halved: 512 WGs = 2 WG/CU for latency hiding.
#define NB 4
#define NN 256
#define DD 256
#define MM 65536

typedef __attribute__((ext_vector_type(8))) __bf16 bf16x8;
typedef __attribute__((ext_vector_type(4))) __bf16 bf16x4;
typedef __attribute__((ext_vector_type(4))) float f32x4;

__device__ __forceinline__ f32x4 mfma_bf16(bf16x8 a, bf16x8 b, f32x4 c) {
    return __builtin_amdgcn_mfma_f32_16x16x32_bf16(a, b, c, 0, 0, 0);
}

// fragment-linear index for a [256 rows][256 cols] B-matrix:
// frag (nt,kk), lane (q,ln) holds row nt*16+ln, cols kk*32+q*8..+8
__device__ __forceinline__ size_t fragidx(int row, int col) {
    int nt = row >> 4, ln = row & 15;
    int kk = col >> 5, q = (col >> 3) & 3, e = col & 7;
    return ((size_t)((nt * 8 + kk) * 64 + q * 16 + ln)) * 8 + e;
}

// ---------------- tiny precompute kernels ----------------

// zeroes accg (G, 1MB) + wg (4KB) which are contiguous: 65792 float4
__global__ void zero_kernel(float* __restrict__ p) {
    reinterpret_cast<float4*>(p)[blockIdx.x * 256 + threadIdx.x] =
        make_float4(0.f, 0.f, 0.f, 0.f);
}

// fused: k = hs@Wk + bk ; kqf[row,e] = (Wq[e,:].k)/16 (frag-linear) ; cb[row] = (bq.k)/16
__global__ void kkq_kernel(const float* __restrict__ hs, const float* __restrict__ Wk,
                           const float* __restrict__ bk, const float* __restrict__ Wq,
                           const float* __restrict__ bq, __bf16* __restrict__ kqf,
                           float* __restrict__ cb) {
    const int row = blockIdx.x, t = threadIdx.x;   // row in [0, NB*NN)
    __shared__ float hr[256];
    __shared__ float kr[256];
    __shared__ float red[256];
    hr[t] = hs[(size_t)row * 256 + t];
    __syncthreads();
    float v = bk[t];
    for (int e = 0; e < 256; ++e)
        v = fmaf(hr[e], Wk[(size_t)e * 256 + t], v);
    kr[t] = v;
    red[t] = v * bq[t];
    __syncthreads();
    float u = 0.f;
    for (int d = 0; d < 256; ++d)
        u = fmaf(Wq[(size_t)t * 256 + d], kr[d], u);
    const int b = row >> 8, n = row & 255;
    kqf[(size_t)b * NN * DD + fragidx(n, t)] = (__bf16)(u * 0.0625f);
    for (int s = 128; s > 0; s >>= 1) {
        if (t < s) red[t] += red[t + s];
        __syncthreads();
    }
    if (t == 0) cb[row] = red[0] * 0.0625f;
}

// wvo[h,e] = sum_d Wv[e,d]*Wo[d,h] (plain [h][e] fp32) ; bvo[h] = bv.Wo[:,h]
__global__ void wvoprep_kernel(const float* __restrict__ Wv, const float* __restrict__ Wo,
                               const float* __restrict__ bv, float* __restrict__ wvo,
                               float* __restrict__ bvo) {
    const int h = blockIdx.x, t = threadIdx.x;
    __shared__ float woc[256];
    __shared__ float red[256];
    float wo = Wo[(size_t)t * 256 + h];
    woc[t] = wo;
    red[t] = bv[t] * wo;
    __syncthreads();
    float v = 0.f;
    for (int d = 0; d < 256; ++d)
        v = fmaf(Wv[(size_t)t * 256 + d], woc[d], v);
    wvo[(size_t)h * 256 + t] = v;
    for (int s = 128; s > 0; s >>= 1) {
        if (t < s) red[t] += red[t + s];
        __syncthreads();
    }
    if (t == 0) bvo[h] = red[0];
}

// ---------------- phase A (v5: scores only; P normalized + S repack; NO atomics) ----
// PT (blocked [m/8][n][8]) = normalized relu(scores)^T, bf16.
// ST (blocked [m/8][d][8]) = bf16(S) — the B-operand for the G contraction.
// One WG = 4 waves = 64 edge-rows; wave w owns rows [w*16, w*16+16).
__global__ __launch_bounds__(256, 3)
void phaseA_kernel(const float* __restrict__ S, const __bf16* __restrict__ kqf,
                   const float* __restrict__ cb, const float* __restrict__ mask,
                   __bf16* __restrict__ PT, __bf16* __restrict__ ST,
                   int c0, int CHS) {
    const int t = threadIdx.x;
    const int b = blockIdx.y;
    const int w = t >> 6;
    const int lane = t & 63;
    const int q = lane >> 4;
    const int ln = lane & 15;
    const int mloc = blockIdx.x * 64 + w * 16;    // wave's base within chunk
    const int m0 = c0 + mloc;                     // global edge base for wave
    const int mb0 = mloc >> 3;                    // local m-block base

    // A-fragments: 16 rows straight from global fp32, convert to bf16
    bf16x8 af[8];
    const float* Ar = S + ((size_t)b * MM + m0 + ln) * DD + q * 8;
#pragma unroll
    for (int kk = 0; kk < 8; ++kk) {
        float4 u0 = *reinterpret_cast<const float4*>(Ar + kk * 32);
        float4 u1 = *reinterpret_cast<const float4*>(Ar + kk * 32 + 4);
        af[kk] = (bf16x8){(__bf16)u0.x, (__bf16)u0.y, (__bf16)u0.z, (__bf16)u0.w,
                          (__bf16)u1.x, (__bf16)u1.y, (__bf16)u1.z, (__bf16)u1.w};
    }

    // ST repack immediately (rows are L2-hot from the A-load):
    // rows m0+aa*8..+8, cols d=(it&3)*64+lane -> coalesced 256B wave reads,
    // contiguous 1KB wave stores into blocked [m/8][d][8] bf16.
    __bf16* Sb = ST + (size_t)b * NN * CHS;
#pragma unroll
    for (int it = 0; it < 8; ++it) {
        const int aa = it >> 2;
        const int d = (it & 3) * 64 + lane;
        const float* Sr = S + ((size_t)b * MM + m0 + aa * 8) * DD + d;
        bf16x8 sv = {(__bf16)Sr[0],      (__bf16)Sr[DD],     (__bf16)Sr[2 * DD],
                     (__bf16)Sr[3 * DD], (__bf16)Sr[4 * DD], (__bf16)Sr[5 * DD],
                     (__bf16)Sr[6 * DD], (__bf16)Sr[7 * DD]};
        *reinterpret_cast<bf16x8*>(Sb + ((size_t)(mb0 + aa) * 256 + d) * 8) = sv;
    }

    // pairwise additive mask for this lane's 4 m-rows
    float m2[4];
#pragma unroll
    for (int r = 0; r < 4; ++r) {
        int mg = m0 + q * 4 + r;
        m2[r] = mask[b * NN + (mg >> 8)] * mask[b * NN + (mg & 255)];
    }

    const __bf16* kqb = kqf + (size_t)b * NN * DD + (size_t)lane * 8;
    const float* cbb = cb + b * NN + ln;

    // ---- scores GEMM: p[nt] = relu(S.kq^T/16 + cb + m2), rowsums in rs*
    f32x4 p[16];
    float rs0 = 0.f, rs1 = 0.f, rs2 = 0.f, rs3 = 0.f;
#pragma unroll
    for (int nt = 0; nt < 16; ++nt) {
        f32x4 a = {0.f, 0.f, 0.f, 0.f};
        const __bf16* kr = kqb + (size_t)nt * 4096;
#pragma unroll
        for (int kk = 0; kk < 8; ++kk) {
            bf16x8 bf = *reinterpret_cast<const bf16x8*>(kr + kk * 512);
            a = mfma_bf16(af[kk], bf, a);
        }
        const float cbv = cbb[nt * 16];
        a.x = fmaxf(a.x + cbv + m2[0], 0.f);
        a.y = fmaxf(a.y + cbv + m2[1], 0.f);
        a.z = fmaxf(a.z + cbv + m2[2], 0.f);
        a.w = fmaxf(a.w + cbv + m2[3], 0.f);
        rs0 += a.x; rs1 += a.y; rs2 += a.z; rs3 += a.w;
        p[nt] = a;
    }
    // rowsum over the 16 n-lanes; ref: probs / sum(probs+1e-12) == probs/(rowsum+256e-12)
#pragma unroll
    for (int off = 1; off < 16; off <<= 1) {
        rs0 += __shfl_xor(rs0, off);
        rs1 += __shfl_xor(rs1, off);
        rs2 += __shfl_xor(rs2, off);
        rs3 += __shfl_xor(rs3, off);
    }
    const float i0 = 1.f / (rs0 + 2.56e-10f);
    const float i1 = 1.f / (rs1 + 2.56e-10f);
    const float i2 = 1.f / (rs2 + 2.56e-10f);
    const float i3 = 1.f / (rs3 + 2.56e-10f);

    // ---- normalized P store (no atomics; w computed in phaseB)
    __bf16* Pb = PT + (size_t)b * NN * CHS;
    const size_t so = (size_t)ln * 8 + (size_t)(q & 1) * 4;
#pragma unroll
    for (int nt = 0; nt < 16; ++nt) {
        bf16x4 pv = {(__bf16)(p[nt].x * i0), (__bf16)(p[nt].y * i1),
                     (__bf16)(p[nt].z * i2), (__bf16)(p[nt].w * i3)};
        *reinterpret_cast<bf16x4*>(Pb + (size_t)(mb0 + (q >> 1)) * 2048
                                   + (size_t)nt * 128 + so) = pv;
    }
}

// ---------------- phase B: G[n,d] += P^T @ S ; w[n] += colsum(P) --------------------
// Blocked layout keeps every fragment load a coalesced 256-B segment; no LDS.
// Grid (4 nh-tiles, CHS/1024 K-chunks, NB) -> 512 WGs = 2 WG/CU (latency hiding).
// w: one gated wave per n-range sums its P-fragment elements (P is normalized).
__global__ __launch_bounds__(256, 2)
void phaseB_kernel(const __bf16* __restrict__ PT, const __bf16* __restrict__ ST,
                   float* __restrict__ accg, float* __restrict__ wg, int CHS) {
    const int t = threadIdx.x;
    const int b = blockIdx.z;
    const int w = t >> 6;
    const int lane = t & 63;
    const int q = lane >> 4;
    const int ln = lane & 15;
    const int n0 = (blockIdx.x >> 1) * 128 + (w >> 1) * 64;
    const int h0 = (blockIdx.x & 1) * 128 + (w & 1) * 64;
    const int g0 = blockIdx.y * 128;           // k-chunk of 1024 m -> 128 blocks of 8
    const bool wgate = ((blockIdx.x & 1) == 0) && ((w & 1) == 0);

    f32x4 acc[16];
#pragma unroll
    for (int i = 0; i < 16; ++i) acc[i] = (f32x4){0.f, 0.f, 0.f, 0.f};
    float wa0 = 0.f, wa1 = 0.f, wa2 = 0.f, wa3 = 0.f;

    const __bf16* Pb = PT + (size_t)b * NN * CHS;
    const __bf16* Vb = ST + (size_t)b * NN * CHS;
#pragma unroll 2
    for (int ks = 0; ks < 32; ++ks) {
        const __bf16* Pk = Pb + ((size_t)(g0 + ks * 4 + q) * 256 + n0 + ln) * 8;
        const __bf16* Vk = Vb + ((size_t)(g0 + ks * 4 + q) * 256 + h0 + ln) * 8;
        bf16x8 a[4], bb[4];
#pragma unroll
        for (int i = 0; i < 4; ++i)
            a[i] = *reinterpret_cast<const bf16x8*>(Pk + i * 128);
#pragma unroll
        for (int j = 0; j < 4; ++j)
            bb[j] = *reinterpret_cast<const bf16x8*>(Vk + j * 128);
#pragma unroll
        for (int i = 0; i < 4; ++i)
#pragma unroll
            for (int j = 0; j < 4; ++j)
                acc[i * 4 + j] = mfma_bf16(a[i], bb[j], acc[i * 4 + j]);
        if (wgate) {
#define WSUM(i, dst)                                                    \
            {                                                           \
                float s = 0.f;                                          \
                _Pragma("unroll")                                       \
                for (int e = 0; e < 8; ++e) s += (float)a[i][e];        \
                dst += s;                                               \
            }
            WSUM(0, wa0) WSUM(1, wa1) WSUM(2, wa2) WSUM(3, wa3)
#undef WSUM
        }
    }
    if (wgate) {   // reduce over the 4 q-groups, one atomic per n (32K total/dispatch)
#define WRED(i, v)                                                      \
        {                                                               \
            float s = v;                                                \
            s += __shfl_xor(s, 16);                                     \
            s += __shfl_xor(s, 32);                                     \
            if (q == 0) atomicAdd(&wg[b * NN + n0 + i * 16 + ln], s);   \
        }
        WRED(0, wa0) WRED(1, wa1) WRED(2, wa2) WRED(3, wa3)
#undef WRED
    }
    float* og = accg + (size_t)b * NN * DD;
#pragma unroll
    for (int i = 0; i < 4; ++i)
#pragma unroll
        for (int j = 0; j < 4; ++j) {
            f32x4 a = acc[i * 4 + j];
            int n = n0 + i * 16 + q * 4;
            int h = h0 + j * 16 + ln;
            atomicAdd(&og[(size_t)(n + 0) * DD + h], a.x);
            atomicAdd(&og[(size_t)(n + 1) * DD + h], a.y);
            atomicAdd(&og[(size_t)(n + 2) * DD + h], a.z);
            atomicAdd(&og[(size_t)(n + 3) * DD + h], a.w);
        }
}

// ---------------- epilogue: ctx = G@wvo^T + w*bvo, +bo, +residual, LayerNorm ----------
__global__ void epilogue_kernel(const float* __restrict__ Gg, const float* __restrict__ wg,
                                const float* __restrict__ wvo, const float* __restrict__ bvo,
                                const float* __restrict__ hs, const float* __restrict__ bo,
                                const float* __restrict__ g, const float* __restrict__ be,
                                float* __restrict__ out) {
    const int row = blockIdx.x, t = threadIdx.x;   // row = b*256 + n, t = h
    __shared__ float Grow[256];
    __shared__ float red[256];
    const size_t base = (size_t)row * 256;
    Grow[t] = Gg[base + t];
    __syncthreads();
    float acc = 0.f;
    const float* wr = wvo + (size_t)t * 256;
    for (int d = 0; d < 256; ++d)
        acc = fmaf(Grow[d], wr[d], acc);
    float x = acc + wg[row] * bvo[t] + bo[t] + hs[base + t];
    red[t] = x;
    __syncthreads();
    for (int s = 128; s > 0; s >>= 1) {
        if (t < s) red[t] += red[t + s];
        __syncthreads();
    }
    float mean = red[0] * (1.f / 256.f);
    __syncthreads();
    float d2 = x - mean;
    red[t] = d2 * d2;
    __syncthreads();
    for (int s = 128; s > 0; s >>= 1) {
        if (t < s) red[t] += red[t + s];
        __syncthreads();
    }
    float var = red[0] * (1.f / 256.f);
    out[base + t] = g[t] * d2 * rsqrtf(var + 1e-5f) + be[t];
}

// ---------------- host launch ----------------
extern "C" void kernel_launch(void* const* d_in, const int* in_sizes, int n_in,
                              void* d_out, int out_size, void* d_ws, size_t ws_size,
                              hipStream_t stream) {
    const float* hs   = (const float*)d_in[0];
    const float* S    = (const float*)d_in[1];
    const float* mask = (const float*)d_in[2];
    const float* Wq   = (const float*)d_in[3];
    const float* bq   = (const float*)d_in[4];
    const float* Wk   = (const float*)d_in[5];
    const float* bk   = (const float*)d_in[6];
    const float* Wv   = (const float*)d_in[7];
    const float* bv   = (const float*)d_in[8];
    const float* Wo   = (const float*)d_in[9];
    const float* bo   = (const float*)d_in[10];
    const float* g    = (const float*)d_in[11];
    const float* be   = (const float*)d_in[12];
    float* out = (float*)d_out;

    char* ws = (char*)d_ws;
    size_t off = 0;
    auto alloc = [&](size_t bytes) {
        void* p = ws + off;
        off += (bytes + 255) & ~(size_t)255;
        return p;
    };
    float*  accg = (float*)alloc((size_t)NB * NN * DD * 4);   // G accumulator (1 MB)
    float*  wg   = (float*)alloc((size_t)NB * NN * 4);        // w accumulator (contiguous)
    __bf16* kqf  = (__bf16*)alloc((size_t)NB * NN * DD * 2);
    float*  cb   = (float*)alloc((size_t)NB * NN * 4);
    float*  wvo  = (float*)alloc((size_t)NN * DD * 4);
    float*  bvo  = (float*)alloc((size_t)NN * 4);
    // chunk of the edge dim: cap at 32768 so a chunk's PT+ST (128 MiB) can stay
    // L3-resident between phaseA write and phaseB read; shrink if ws small.
    size_t rem = ws_size > off ? ws_size - off : 0;
    int CH = 32768;
    while (CH > 4096 && (size_t)CH * 4096 + 1024 > rem) CH >>= 1;
    __bf16* PT = (__bf16*)alloc((size_t)NB * CH * NN * 2);
    __bf16* ST = (__bf16*)alloc((size_t)NB * CH * NN * 2);

    zero_kernel<<<257, 256, 0, stream>>>(accg);   // zeroes accg + wg (contiguous)
    kkq_kernel<<<NB * NN, 256, 0, stream>>>(hs, Wk, bk, Wq, bq, kqf, cb);
    wvoprep_kernel<<<NN, 256, 0, stream>>>(Wv, Wo, bv, wvo, bvo);
    for (int c0 = 0; c0 < MM; c0 += CH) {
        phaseA_kernel<<<dim3(CH / 64, NB), 256, 0, stream>>>(S, kqf, cb, mask,
                                                             PT, ST, c0, CH);
        phaseB_kernel<<<dim3(4, CH / 1024, NB), 256, 0, stream>>>(PT, ST, accg, wg, CH);
    }
    epilogue_kernel<<<NB * NN, 256, 0, stream>>>(accg, wg, wvo, bvo, hs, bo, g, be, out);
}